// Round 7
// baseline (5308.128 us; speedup 1.0000x reference)
//
#include <hip/hip_runtime.h>
#include <cstdint>

// LSTM fused kernel for MI355X — round 9: lean MFMA recurrence.
// 16 blocks x 1024 threads (16 waves, 4/SIMD), MB=4 batches per block.
// Wave wvi owns N-tiles [wvi*4, wvi*4+4) -> each thread = 1 h-unit, its 4
// gates in-lane (C[nt][0], nt=0..3). Whh int8 B-frags STREAMED from L2 each
// step (constant addresses, 256KB resident) to fit the 128-VGPR/16-wave
// budget; Wih f16 frags resident; shared-zero C operands (no init movs).
// Per-batch h-scale: row16 DPP max -> 16 LDS slots -> each thread reduces
// post-B1 and CARRIES the scale in a register to t+1 (no atomics, no scale
// re-read). fc runs every 4 steps with real M=16 (4 batches x 4 timesteps,
// 4-deep hf ring) on waves 0-1. Two raw s_barriers/step, lgkm-only drains.
// ws 8.4 MB (< proven 51.2 MB floor).

#define B_  64
#define T_  2048
#define I_  32
#define H_  256
#define O_  32
#define MB  4
#define NBLK 16

typedef int v4i __attribute__((ext_vector_type(4)));
typedef unsigned int v4u __attribute__((ext_vector_type(4)));
typedef float f32x4 __attribute__((ext_vector_type(4)));
typedef _Float16 f16x8 __attribute__((ext_vector_type(8)));
typedef _Float16 h2_t __attribute__((ext_vector_type(2)));

union U16x8 { v4u u; f16x8 h; };

// max over each 16-lane DPP row via row_shr; lane (16k+15) holds row max.
__device__ __forceinline__ float row16_max(float v) {
    int t;
    t = __builtin_amdgcn_update_dpp(__float_as_int(v), __float_as_int(v), 0x111, 0xf, 0xf, false);
    v = fmaxf(v, __int_as_float(t));
    t = __builtin_amdgcn_update_dpp(__float_as_int(v), __float_as_int(v), 0x112, 0xf, 0xf, false);
    v = fmaxf(v, __int_as_float(t));
    t = __builtin_amdgcn_update_dpp(__float_as_int(v), __float_as_int(v), 0x114, 0xf, 0xf, false);
    v = fmaxf(v, __int_as_float(t));
    t = __builtin_amdgcn_update_dpp(__float_as_int(v), __float_as_int(v), 0x118, 0xf, 0xf, false);
    v = fmaxf(v, __int_as_float(t));
    return v;
}

// ---------------- ws layout (8.4 MB total) ----------------
// wq2   : int8 Whh B-frags, dword idx ((c>>4)*16 + kt*4+lq)*64 + (c&15)*4 + e
// s1p   : f32 per-col Whh scale (c-order)
// biasp : f32 per-col bias (c-order)
// wihh2 : f16 Wih B-frags, dword idx ((c>>4)*4 + lq)*64 + (c&15)*4 + e
// fcf   : f16 fcw B-frags, dword idx ((ntile*8+ks)*64 + l)*4 + e
// xh    : f16 x [B][T][32]
#define WQ_OFF    0
#define S1P_OFF   262144
#define BIASP_OFF 266240
#define WIHH2_OFF 270336
#define FCF_OFF   335872
#define XH_OFF    352256
// end: 8740864 bytes

__device__ __forceinline__ uint32_t pack_q(int q0, int q1, int q2, int q3) {
    return  ((uint32_t)(uint8_t)(int8_t)q0)
          | (((uint32_t)(uint8_t)(int8_t)q1) << 8)
          | (((uint32_t)(uint8_t)(int8_t)q2) << 16)
          | (((uint32_t)(uint8_t)(int8_t)q3) << 24);
}

__device__ __forceinline__ int clamp127(int v) {
    return v < -127 ? -127 : (v > 127 ? 127 : v);
}

// c-permutation: col c for gate-row (g, r):  c = ((r>>4)<<6) | (g<<4) | (r&15)
// kernel side: tile ti = c>>4 = wvi*4+nt  ->  g = nt, r = wvi*16 + lo.

// -------- prep: Whh -> int8 B-frags (per-gate-row scale), Wih -> f16 B-frags --------
__global__ __launch_bounds__(64) void prep_wq(
    const float* __restrict__ Whh, const float* __restrict__ Wih,
    const float* __restrict__ bih, const float* __restrict__ bhh,
    uint32_t* __restrict__ wq2, float* __restrict__ s1p,
    float* __restrict__ biasp, uint32_t* __restrict__ wihh2)
{
    const int gr = blockIdx.x;          // gate-row 0..1023
    const int j  = threadIdx.x;         // k-dword 0..63
    const int g  = gr >> 8, r = gr & 255;
    const int c  = ((r >> 4) << 6) | (g << 4) | (r & 15);

    const float4 wv = ((const float4*)(Whh + gr * H_))[j];
    float m = fmaxf(fmaxf(fabsf(wv.x), fabsf(wv.y)), fmaxf(fabsf(wv.z), fabsf(wv.w)));
    #pragma unroll
    for (int s = 1; s < 64; s <<= 1) m = fmaxf(m, __shfl_xor(m, s, 64));
    const float S1 = fmaxf(m, 1e-20f) / 127.f;
    const float r1 = 1.f / S1;

    wq2[((c >> 4) * 16 + (j >> 2)) * 64 + (c & 15) * 4 + (j & 3)] = pack_q(
        clamp127((int)rintf(wv.x * r1)), clamp127((int)rintf(wv.y * r1)),
        clamp127((int)rintf(wv.z * r1)), clamp127((int)rintf(wv.w * r1)));

    if (j < 16) {   // Wih f16 pair dword: k = 2j, 2j+1
        union { uint32_t u; h2_t h; } z;
        z.h[0] = (_Float16)Wih[gr * I_ + 2 * j];
        z.h[1] = (_Float16)Wih[gr * I_ + 2 * j + 1];
        wihh2[((c >> 4) * 4 + (j >> 2)) * 64 + (c & 15) * 4 + (j & 3)] = z.u;
    }
    if (j == 0) { s1p[c] = S1; biasp[c] = bih[gr] + bhh[gr]; }
}

// -------- prep: x f32 -> f16 pairs --------
__global__ __launch_bounds__(256) void prep_xh(
    const float* __restrict__ x, uint32_t* __restrict__ xh)
{
    const int i = blockIdx.x * 256 + threadIdx.x;   // dword index < B*T*16
    const float2 v = ((const float2*)x)[i];
    union { uint32_t u; h2_t h; } z;
    z.h[0] = (_Float16)v.x; z.h[1] = (_Float16)v.y;
    xh[i] = z.u;
}

// -------- prep: fcw f32 -> f16 B-frags (fc MFMA: A=h rows, B=fcw cols) --------
// B-frag lane l: col o = ntile*16 + (l&15), k = ks*32 + (l>>4)*8 + 2e(+1)
__global__ __launch_bounds__(64) void prep_fcf(
    const float* __restrict__ fcw, uint32_t* __restrict__ fcf)
{
    const int id = blockIdx.x * 64 + threadIdx.x;   // 0..1023
    const int ntile = id >> 9, ks = (id >> 6) & 7, l = id & 63;
    const int o  = ntile * 16 + (l & 15);
    const int kb = ks * 32 + (l >> 4) * 8;
    const float* src = fcw + o * H_ + kb;
    #pragma unroll
    for (int e = 0; e < 4; e++) {
        union { uint32_t u; h2_t h; } z;
        z.h[0] = (_Float16)src[2 * e];
        z.h[1] = (_Float16)src[2 * e + 1];
        fcf[id * 4 + e] = z.u;
    }
}

// -------- main: 16 blocks x 1024 threads, MFMA recurrence --------
__global__ __launch_bounds__(1024) void lstm_mfma(
    const uint32_t* __restrict__ wq2, const float* __restrict__ s1p,
    const float* __restrict__ biasp, const uint32_t* __restrict__ wihh2,
    const uint32_t* __restrict__ xh, const uint32_t* __restrict__ fcf,
    const float* __restrict__ fcb, float* __restrict__ out)
{
    const int blk = blockIdx.x, tid = threadIdx.x;
    const int wvi = tid >> 6, l = tid & 63, lq = l >> 4, lo = l & 15;
    const int xb_ = lo >> 2;            // A-side batch (rows duplicated x4)

    __shared__ __align__(16) char     Ab[2][1088];   // int8 h, row stride 272
    __shared__ __align__(16) _Float16 hf[4][1088];   // f16 h ring (for fc)
    __shared__ __align__(16) float    smax[4][16];   // [batch][wave] |h| maxes

    // resident Wih f16 B-frags + per-col scale/bias (4 tiles of this wave)
    U16x8 wX[4];
    float s1c[4], biasc[4];
    #pragma unroll
    for (int nt = 0; nt < 4; nt++) {
        const int ti = wvi * 4 + nt;
        const int c  = ti * 16 + lo;
        s1c[nt] = s1p[c]; biasc[nt] = biasp[c];
        wX[nt].u = *(const v4u*)(wihh2 + (size_t)((ti * 4 + lq) * 64 + lo * 4));
    }
    const float fb = fcb[(wvi & 1) * 16 + lo];   // fc bias (waves 0-1 use it)

    // init: zero h(-1) int8 buffer (t=0 reads buffer 1)
    if (tid < 272) ((uint32_t*)&Ab[1][0])[tid] = 0;
    __syncthreads();

    const uint32_t* xrow = xh + ((size_t)(blk * MB + xb_) * T_) * 16 + lq * 4;
    v4u xA = *(const v4u*)xrow;          // x A-frag for t=0

    const v4i z4 = {0, 0, 0, 0};
    float cst = 0.f;     // c-state of (batch lq, row wvi*16+lo)
    float sp  = 0.f;     // prev h quant scale of batch lq, register-carried

    for (int t = 0; t < T_; t++) {
        const int rb = (t & 1) ^ 1, cb = t & 1;

        // A fragments (broadcast ds_reads; rows = batches, k = h-rows)
        const v4i af0 = *(const v4i*)&Ab[rb][xb_ * 272 +   0 + lq * 16];
        const v4i af1 = *(const v4i*)&Ab[rb][xb_ * 272 +  64 + lq * 16];
        const v4i af2 = *(const v4i*)&Ab[rb][xb_ * 272 + 128 + lq * 16];
        const v4i af3 = *(const v4i*)&Ab[rb][xb_ * 272 + 192 + lq * 16];

        // next-step x prefetch (L2/L3 resident)
        const int tn = (t + 1 < T_) ? (t + 1) : t;
        const v4u xAn = *(const v4u*)(xrow + (size_t)tn * 16);

        // gates: per nt, 4 streamed-wB int8 MFMAs + 1 f16 x-MFMA, zero C-in
        U16x8 xa; xa.u = xA;
        float ga[4];
        #pragma unroll
        for (int nt = 0; nt < 4; nt++) {
            const int ti = wvi * 4 + nt;
            const uint32_t* wp = wq2 + (size_t)((ti * 16 + lq) * 64 + lo * 4);
            const v4i w0 = *(const v4i*)(wp);
            const v4i w1 = *(const v4i*)(wp + 256);
            const v4i w2 = *(const v4i*)(wp + 512);
            const v4i w3 = *(const v4i*)(wp + 768);
            v4i ci = __builtin_amdgcn_mfma_i32_16x16x64_i8(af0, w0, z4, 0, 0, 0);
            ci = __builtin_amdgcn_mfma_i32_16x16x64_i8(af1, w1, ci, 0, 0, 0);
            ci = __builtin_amdgcn_mfma_i32_16x16x64_i8(af2, w2, ci, 0, 0, 0);
            ci = __builtin_amdgcn_mfma_i32_16x16x64_i8(af3, w3, ci, 0, 0, 0);
            f32x4 zf = {0.f, 0.f, 0.f, 0.f};
            const f32x4 cfx = __builtin_amdgcn_mfma_f32_16x16x32_f16(xa.h, wX[nt].h, zf, 0, 0, 0);
            ga[nt] = cfx[0] + biasc[nt] + (float)ci[0] * (s1c[nt] * sp);
        }

        // fc burst every 4 steps on waves 0-1: real M = 4 batches x 4 steps
        if ((t & 3) == 0 && t > 0 && wvi < 2) {
            const int ts = lo >> 2, fbb = lo & 3;      // A row m = 4*ts + b
            f32x4 cfc = {0.f, 0.f, 0.f, 0.f};
            #pragma unroll
            for (int ks = 0; ks < 8; ks++) {
                U16x8 aH, bB;
                aH.u = *(const v4u*)&hf[(t + ts) & 3][fbb * 272 + ks * 32 + lq * 8];
                bB.u = *(const v4u*)(fcf + (size_t)(((wvi * 8 + ks) * 64 + l) * 4));
                cfc = __builtin_amdgcn_mfma_f32_16x16x32_f16(aH.h, bB.h, cfc, 0, 0, 0);
            }
            // D row 4lq+reg -> (ts=lq, batch=reg); col o = wvi*16+lo
            #pragma unroll
            for (int reg = 0; reg < 4; reg++)
                out[((size_t)(blk * MB + reg) * T_ + (t - 4 + lq)) * O_
                    + (wvi * 16 + lo)] = cfc[reg] + fb;   // fire & forget
        }

        // nonlinearity (exactly one h-unit per thread)
        const float i_ = 1.f / (1.f + __expf(-ga[0]));
        const float f_ = 1.f / (1.f + __expf(-ga[1]));
        const float g_ = 2.f / (1.f + __expf(-2.f * ga[2])) - 1.f;
        const float o_ = 1.f / (1.f + __expf(-ga[3]));
        cst = f_ * cst + i_ * g_;
        const float tc = 2.f / (1.f + __expf(-2.f * cst)) - 1.f;
        const float h = o_ * tc;

        // per-batch |h| max: row16 DPP + plain-store tree (no atomics)
        const float vm = row16_max(fabsf(h));
        if (lo == 15) smax[lq][wvi] = vm;

        asm volatile("s_waitcnt lgkmcnt(0)" ::: "memory");
        __builtin_amdgcn_s_barrier();                    // B1: maxes published

        // every thread reduces its batch's 16 wave-maxes; scale kept in reg
        const float4 m0 = *(const float4*)&smax[lq][0];
        const float4 m1 = *(const float4*)&smax[lq][4];
        const float4 m2 = *(const float4*)&smax[lq][8];
        const float4 m3 = *(const float4*)&smax[lq][12];
        float mm = fmaxf(fmaxf(fmaxf(m0.x, m0.y), fmaxf(m0.z, m0.w)),
                         fmaxf(fmaxf(m1.x, m1.y), fmaxf(m1.z, m1.w)));
        mm = fmaxf(mm, fmaxf(fmaxf(fmaxf(m2.x, m2.y), fmaxf(m2.z, m2.w)),
                             fmaxf(fmaxf(m3.x, m3.y), fmaxf(m3.z, m3.w))));
        mm = fmaxf(mm, 1e-12f);
        const float rq = 127.f / mm;
        const int r0 = wvi * 16 + lo;
        Ab[cb][lq * 272 + r0] = (char)(int8_t)clamp127((int)rintf(h * rq));
        hf[t & 3][lq * 272 + r0] = (_Float16)h;
        sp = mm * (1.f / 127.f);                         // dequant scale for t+1

        asm volatile("s_waitcnt lgkmcnt(0)" ::: "memory");
        __builtin_amdgcn_s_barrier();                    // B2: h(t) published

        xA = xAn;
    }

    // epilogue fc: window T-4..T-1
    if (wvi < 2) {
        const int ts = lo >> 2, fbb = lo & 3;
        f32x4 cfc = {0.f, 0.f, 0.f, 0.f};
        #pragma unroll
        for (int ks = 0; ks < 8; ks++) {
            U16x8 aH, bB;
            aH.u = *(const v4u*)&hf[ts & 3][fbb * 272 + ks * 32 + lq * 8];
            bB.u = *(const v4u*)(fcf + (size_t)(((wvi * 8 + ks) * 64 + l) * 4));
            cfc = __builtin_amdgcn_mfma_f32_16x16x32_f16(aH.h, bB.h, cfc, 0, 0, 0);
        }
        #pragma unroll
        for (int reg = 0; reg < 4; reg++)
            out[((size_t)(blk * MB + reg) * T_ + (T_ - 4 + lq)) * O_
                + (wvi * 16 + lo)] = cfc[reg] + fb;
    }
}

// ======================= launch =======================
extern "C" void kernel_launch(void* const* d_in, const int* in_sizes, int n_in,
                              void* d_out, int out_size, void* d_ws, size_t ws_size,
                              hipStream_t stream) {
    const float* x    = (const float*)d_in[0];
    const float* Wih  = (const float*)d_in[1];
    const float* Whh  = (const float*)d_in[2];
    const float* bih  = (const float*)d_in[3];
    const float* bhh  = (const float*)d_in[4];
    const float* fcw  = (const float*)d_in[5];
    const float* fcb  = (const float*)d_in[6];
    float* out = (float*)d_out;

    char* ws = (char*)d_ws;
    uint32_t* wq2   = (uint32_t*)(ws + WQ_OFF);
    float*    s1p   = (float*)(ws + S1P_OFF);
    float*    biasp = (float*)(ws + BIASP_OFF);
    uint32_t* wihh2 = (uint32_t*)(ws + WIHH2_OFF);
    uint32_t* fcf   = (uint32_t*)(ws + FCF_OFF);
    uint32_t* xh    = (uint32_t*)(ws + XH_OFF);

    prep_wq<<<1024, 64, 0, stream>>>(Whh, Wih, bih, bhh, wq2, s1p, biasp, wihh2);
    prep_xh<<<(B_ * T_ * 16) / 256, 256, 0, stream>>>(x, xh);
    prep_fcf<<<16, 64, 0, stream>>>(fcw, fcf);
    lstm_mfma<<<NBLK, 1024, 0, stream>>>(wq2, s1p, biasp, wihh2, xh, fcf, fcb, out);
}

// Round 8
// 3856.841 us; speedup vs baseline: 1.3763x; 1.3763x over previous
//
#include <hip/hip_runtime.h>
#include <cstdint>

// LSTM fused kernel for MI355X — round 10: r8 skeleton + VALU diet.
// 16 blocks x 512 threads (8 waves, 2/SIMD), MB=4 batches per block.
// All weights RESIDENT (wB int8 in unified/AGPR file, wX f16 in VGPRs) —
// r9's L2 streaming regression reverted. Per step: 32 i8 MFMA + 8 f16 x-MFMA
// per wave (r8-verified fragment maps), zero-C shared operand, 2 raw
// s_barriers with lgkm-only drains. VALU cuts vs r8 (its 2480cy VALU bill):
// no hist global stores (fc windowed every 4 steps from 4-deep LDS hf ring,
// r9-verified), no atomicMax (plain smax[batch][wave] + 8-wide reduce),
// scale carried in-register, precomputed fc out-pointers, pointer-increment
// x prefetch. ws 8.4 MB (< proven 51.2 MB floor).

#define B_  64
#define T_  2048
#define I_  32
#define H_  256
#define O_  32
#define MB  4
#define NBLK 16

typedef int v4i __attribute__((ext_vector_type(4)));
typedef unsigned int v4u __attribute__((ext_vector_type(4)));
typedef float f32x4 __attribute__((ext_vector_type(4)));
typedef _Float16 f16x8 __attribute__((ext_vector_type(8)));
typedef _Float16 h2_t __attribute__((ext_vector_type(2)));

union U16x8 { v4u u; f16x8 h; };

// max over each 16-lane DPP row via row_shr; lane (16k+15) holds row max.
__device__ __forceinline__ float row16_max(float v) {
    int t;
    t = __builtin_amdgcn_update_dpp(__float_as_int(v), __float_as_int(v), 0x111, 0xf, 0xf, false);
    v = fmaxf(v, __int_as_float(t));
    t = __builtin_amdgcn_update_dpp(__float_as_int(v), __float_as_int(v), 0x112, 0xf, 0xf, false);
    v = fmaxf(v, __int_as_float(t));
    t = __builtin_amdgcn_update_dpp(__float_as_int(v), __float_as_int(v), 0x114, 0xf, 0xf, false);
    v = fmaxf(v, __int_as_float(t));
    t = __builtin_amdgcn_update_dpp(__float_as_int(v), __float_as_int(v), 0x118, 0xf, 0xf, false);
    v = fmaxf(v, __int_as_float(t));
    return v;
}

// ---------------- ws layout (8.4 MB total) ----------------
#define WQ_OFF    0
#define S1P_OFF   262144
#define BIASP_OFF 266240
#define WIHH2_OFF 270336
#define FCF_OFF   335872
#define XH_OFF    352256
// end: 8740864 bytes

__device__ __forceinline__ uint32_t pack_q(int q0, int q1, int q2, int q3) {
    return  ((uint32_t)(uint8_t)(int8_t)q0)
          | (((uint32_t)(uint8_t)(int8_t)q1) << 8)
          | (((uint32_t)(uint8_t)(int8_t)q2) << 16)
          | (((uint32_t)(uint8_t)(int8_t)q3) << 24);
}

__device__ __forceinline__ int clamp127(int v) {
    return v < -127 ? -127 : (v > 127 ? 127 : v);
}

// c-permutation: col c for gate-row (g, r):  c = ((r>>4)<<6) | (g<<4) | (r&15)
// kernel: ti = wvi*8+nt -> g = nt&3, r = (wvi*2 + (nt>=4))*16 + lo.

// -------- prep: Whh -> int8 B-frags (per-gate-row scale), Wih -> f16 B-frags --------
__global__ __launch_bounds__(64) void prep_wq(
    const float* __restrict__ Whh, const float* __restrict__ Wih,
    const float* __restrict__ bih, const float* __restrict__ bhh,
    uint32_t* __restrict__ wq2, float* __restrict__ s1p,
    float* __restrict__ biasp, uint32_t* __restrict__ wihh2)
{
    const int gr = blockIdx.x;          // gate-row 0..1023
    const int j  = threadIdx.x;         // k-dword 0..63
    const int g  = gr >> 8, r = gr & 255;
    const int c  = ((r >> 4) << 6) | (g << 4) | (r & 15);

    const float4 wv = ((const float4*)(Whh + gr * H_))[j];
    float m = fmaxf(fmaxf(fabsf(wv.x), fabsf(wv.y)), fmaxf(fabsf(wv.z), fabsf(wv.w)));
    #pragma unroll
    for (int s = 1; s < 64; s <<= 1) m = fmaxf(m, __shfl_xor(m, s, 64));
    const float S1 = fmaxf(m, 1e-20f) / 127.f;
    const float r1 = 1.f / S1;

    wq2[((c >> 4) * 16 + (j >> 2)) * 64 + (c & 15) * 4 + (j & 3)] = pack_q(
        clamp127((int)rintf(wv.x * r1)), clamp127((int)rintf(wv.y * r1)),
        clamp127((int)rintf(wv.z * r1)), clamp127((int)rintf(wv.w * r1)));

    if (j < 16) {   // Wih f16 pair dword: k = 2j, 2j+1
        union { uint32_t u; h2_t h; } z;
        z.h[0] = (_Float16)Wih[gr * I_ + 2 * j];
        z.h[1] = (_Float16)Wih[gr * I_ + 2 * j + 1];
        wihh2[((c >> 4) * 4 + (j >> 2)) * 64 + (c & 15) * 4 + (j & 3)] = z.u;
    }
    if (j == 0) { s1p[c] = S1; biasp[c] = bih[gr] + bhh[gr]; }
}

// -------- prep: x f32 -> f16 pairs --------
__global__ __launch_bounds__(256) void prep_xh(
    const float* __restrict__ x, uint32_t* __restrict__ xh)
{
    const int i = blockIdx.x * 256 + threadIdx.x;   // dword index < B*T*16
    const float2 v = ((const float2*)x)[i];
    union { uint32_t u; h2_t h; } z;
    z.h[0] = (_Float16)v.x; z.h[1] = (_Float16)v.y;
    xh[i] = z.u;
}

// -------- prep: fcw f32 -> f16 B-frags (fc MFMA: A=h rows, B=fcw cols) --------
__global__ __launch_bounds__(64) void prep_fcf(
    const float* __restrict__ fcw, uint32_t* __restrict__ fcf)
{
    const int id = blockIdx.x * 64 + threadIdx.x;   // 0..1023
    const int ntile = id >> 9, ks = (id >> 6) & 7, l = id & 63;
    const int o  = ntile * 16 + (l & 15);
    const int kb = ks * 32 + (l >> 4) * 8;
    const float* src = fcw + o * H_ + kb;
    #pragma unroll
    for (int e = 0; e < 4; e++) {
        union { uint32_t u; h2_t h; } z;
        z.h[0] = (_Float16)src[2 * e];
        z.h[1] = (_Float16)src[2 * e + 1];
        fcf[id * 4 + e] = z.u;
    }
}

// -------- main: 16 blocks x 512 threads, MFMA recurrence --------
__global__ __launch_bounds__(512, 2) void lstm_mfma(
    const uint32_t* __restrict__ wq2, const float* __restrict__ s1p,
    const float* __restrict__ biasp, const uint32_t* __restrict__ wihh2,
    const uint32_t* __restrict__ xh, const uint32_t* __restrict__ fcf,
    const float* __restrict__ fcb, float* __restrict__ out)
{
    const int blk = blockIdx.x, tid = threadIdx.x;
    const int wvi = tid >> 6, l = tid & 63, lq = l >> 4, lo = l & 15;
    const int xb_ = lo >> 2;            // A-side batch (rows duplicated x4)

    __shared__ __align__(16) char     Ab[2][1088];   // int8 h, row stride 272
    __shared__ __align__(16) _Float16 hf[4][1088];   // f16 h ring (for fc)
    __shared__ __align__(16) float    smax[4][8];    // [batch][wave] |h| maxes

    // ---- resident weights (r8-verified fragment layouts) ----
    v4i   wB[8][4];
    U16x8 wX[8];
    float s1c[8], biasc[8];
    #pragma unroll
    for (int nt = 0; nt < 8; nt++) {
        const int c = wvi * 128 + nt * 16 + lo;
        s1c[nt] = s1p[c]; biasc[nt] = biasp[c];
        #pragma unroll
        for (int kt = 0; kt < 4; kt++)
            wB[nt][kt] = *(const v4i*)(wq2 +
                (size_t)(((wvi * 8 + nt) * 16 + kt * 4 + lq) * 64 + lo * 4));
        wX[nt].u = *(const v4u*)(wihh2 +
                (size_t)(((wvi * 8 + nt) * 4 + lq) * 64 + lo * 4));
    }

    // fc setup (used by waves 0-1; computed uniformly, cheap)
    const uint32_t* fcp = fcf + (size_t)((wvi & 1) * 512 + l) * 4;
    const float fb = fcb[(wvi & 1) * 16 + lo];
    float* outp0 = out + ((size_t)(blk * MB + 0) * T_ + lq) * O_ + ((wvi & 1) * 16 + lo);
    float* outp1 = out + ((size_t)(blk * MB + 1) * T_ + lq) * O_ + ((wvi & 1) * 16 + lo);
    float* outp2 = out + ((size_t)(blk * MB + 2) * T_ + lq) * O_ + ((wvi & 1) * 16 + lo);
    float* outp3 = out + ((size_t)(blk * MB + 3) * T_ + lq) * O_ + ((wvi & 1) * 16 + lo);

    // init: zero h(-1) int8 buffer (t=0 reads buffer 1)
    if (tid < 272) ((uint32_t*)&Ab[1][0])[tid] = 0;
    __syncthreads();

    const uint32_t* xp = xh + ((size_t)(blk * MB + xb_) * T_) * 16 + lq * 4;
    v4u xA = *(const v4u*)xp;            // x A-frag for t=0
    const uint32_t* xpn = xp + 16;       // running prefetch pointer

    const v4i  z4 = {0, 0, 0, 0};
    const f32x4 zf = {0.f, 0.f, 0.f, 0.f};
    float cst0 = 0.f, cst1 = 0.f;        // c-states of rows r0, r1 (batch lq)
    float sp = 0.f;                      // prev h dequant scale (batch lq)

    for (int t = 0; t < T_; t++) {
        const int rb = (t & 1) ^ 1, cb = t & 1;

        // A fragments (broadcast ds_reads: 4 lanes share each 16B)
        const char* ab = &Ab[rb][xb_ * 272 + lq * 16];
        const v4i af0 = *(const v4i*)(ab);
        const v4i af1 = *(const v4i*)(ab + 64);
        const v4i af2 = *(const v4i*)(ab + 128);
        const v4i af3 = *(const v4i*)(ab + 192);

        // next-step x prefetch (running pointer; final-step overread is
        // within ws and unused)
        const v4u xAn = *(const v4u*)xpn;

        // gates: per nt, 4 resident-wB i8 MFMAs + 1 f16 x-MFMA, shared zero C
        U16x8 xa; xa.u = xA;
        float ga[8];
        #pragma unroll
        for (int nt = 0; nt < 8; nt++) {
            v4i ci;
            ci = __builtin_amdgcn_mfma_i32_16x16x64_i8(af0, wB[nt][0], z4, 0, 0, 0);
            ci = __builtin_amdgcn_mfma_i32_16x16x64_i8(af1, wB[nt][1], ci, 0, 0, 0);
            ci = __builtin_amdgcn_mfma_i32_16x16x64_i8(af2, wB[nt][2], ci, 0, 0, 0);
            ci = __builtin_amdgcn_mfma_i32_16x16x64_i8(af3, wB[nt][3], ci, 0, 0, 0);
            const f32x4 cfx = __builtin_amdgcn_mfma_f32_16x16x32_f16(xa.h, wX[nt].h, zf, 0, 0, 0);
            ga[nt] = cfx[0] + biasc[nt] + (float)ci[0] * (s1c[nt] * sp);
        }

        // fc burst every 4 steps on waves 0-1 (A = hf ring, B = fcf; r9-verified)
        if ((t & 3) == 0 && t > 0 && wvi < 2) {
            const int ts = lo >> 2, fbb = lo & 3;      // A row m = 4*ts + fbb
            f32x4 cfc = zf;
            #pragma unroll
            for (int ks = 0; ks < 8; ks++) {
                U16x8 aH, bB;
                aH.u = *(const v4u*)&hf[(t + ts) & 3][fbb * 272 + ks * 32 + lq * 8];
                bB.u = *(const v4u*)(fcp + (size_t)ks * 256);
                cfc = __builtin_amdgcn_mfma_f32_16x16x32_f16(aH.h, bB.h, cfc, 0, 0, 0);
            }
            const int off = (t - 4) * O_;              // D row 4lq+reg -> (t-4+lq, batch reg)
            outp0[off] = cfc[0] + fb;
            outp1[off] = cfc[1] + fb;
            outp2[off] = cfc[2] + fb;
            outp3[off] = cfc[3] + fb;                  // fire & forget
        }

        // nonlinearity: 2 units (batch lq; rows wvi*32+lo, +16)
        const float i0 = 1.f / (1.f + __expf(-ga[0]));
        const float f0 = 1.f / (1.f + __expf(-ga[1]));
        const float g0 = 2.f / (1.f + __expf(-2.f * ga[2])) - 1.f;
        const float o0 = 1.f / (1.f + __expf(-ga[3]));
        cst0 = f0 * cst0 + i0 * g0;
        const float h0 = o0 * (2.f / (1.f + __expf(-2.f * cst0)) - 1.f);

        const float i1 = 1.f / (1.f + __expf(-ga[4]));
        const float f1 = 1.f / (1.f + __expf(-ga[5]));
        const float g1 = 2.f / (1.f + __expf(-2.f * ga[6])) - 1.f;
        const float o1 = 1.f / (1.f + __expf(-ga[7]));
        cst1 = f1 * cst1 + i1 * g1;
        const float h1 = o1 * (2.f / (1.f + __expf(-2.f * cst1)) - 1.f);

        // per-(wave,batch) |h| max -> plain LDS store (no atomics)
        const float vm = row16_max(fmaxf(fabsf(h0), fabsf(h1)));
        if (lo == 15) smax[lq][wvi] = vm;

        asm volatile("s_waitcnt lgkmcnt(0)" ::: "memory");
        __builtin_amdgcn_s_barrier();                    // B1: maxes published

        // reduce 8 wave-maxes of batch lq; scale carried in register
        const float4 m0 = *(const float4*)&smax[lq][0];
        const float4 m1 = *(const float4*)&smax[lq][4];
        float mm = fmaxf(fmaxf(fmaxf(m0.x, m0.y), fmaxf(m0.z, m0.w)),
                         fmaxf(fmaxf(m1.x, m1.y), fmaxf(m1.z, m1.w)));
        mm = fmaxf(mm, 1e-12f);
        const float rq = 127.f / mm;
        const int r0 = wvi * 32 + lo, r1 = r0 + 16;
        Ab[cb][lq * 272 + r0] = (char)(int8_t)clamp127((int)rintf(h0 * rq));
        Ab[cb][lq * 272 + r1] = (char)(int8_t)clamp127((int)rintf(h1 * rq));
        hf[t & 3][lq * 272 + r0] = (_Float16)h0;
        hf[t & 3][lq * 272 + r1] = (_Float16)h1;
        sp = mm * (1.f / 127.f);                         // dequant scale for t+1

        asm volatile("s_waitcnt lgkmcnt(0)" ::: "memory");
        __builtin_amdgcn_s_barrier();                    // B2: h(t) published

        xA = xAn; xpn += 16;
    }

    // epilogue fc: window T-4..T-1
    if (wvi < 2) {
        const int ts = lo >> 2, fbb = lo & 3;
        f32x4 cfc = zf;
        #pragma unroll
        for (int ks = 0; ks < 8; ks++) {
            U16x8 aH, bB;
            aH.u = *(const v4u*)&hf[ts & 3][fbb * 272 + ks * 32 + lq * 8];
            bB.u = *(const v4u*)(fcp + (size_t)ks * 256);
            cfc = __builtin_amdgcn_mfma_f32_16x16x32_f16(aH.h, bB.h, cfc, 0, 0, 0);
        }
        const int off = (T_ - 4) * O_;
        outp0[off] = cfc[0] + fb;
        outp1[off] = cfc[1] + fb;
        outp2[off] = cfc[2] + fb;
        outp3[off] = cfc[3] + fb;
    }
}

// ======================= launch =======================
extern "C" void kernel_launch(void* const* d_in, const int* in_sizes, int n_in,
                              void* d_out, int out_size, void* d_ws, size_t ws_size,
                              hipStream_t stream) {
    const float* x    = (const float*)d_in[0];
    const float* Wih  = (const float*)d_in[1];
    const float* Whh  = (const float*)d_in[2];
    const float* bih  = (const float*)d_in[3];
    const float* bhh  = (const float*)d_in[4];
    const float* fcw  = (const float*)d_in[5];
    const float* fcb  = (const float*)d_in[6];
    float* out = (float*)d_out;

    char* ws = (char*)d_ws;
    uint32_t* wq2   = (uint32_t*)(ws + WQ_OFF);
    float*    s1p   = (float*)(ws + S1P_OFF);
    float*    biasp = (float*)(ws + BIASP_OFF);
    uint32_t* wihh2 = (uint32_t*)(ws + WIHH2_OFF);
    uint32_t* fcf   = (uint32_t*)(ws + FCF_OFF);
    uint32_t* xh    = (uint32_t*)(ws + XH_OFF);

    prep_wq<<<1024, 64, 0, stream>>>(Whh, Wih, bih, bhh, wq2, s1p, biasp, wihh2);
    prep_xh<<<(B_ * T_ * 16) / 256, 256, 0, stream>>>(x, xh);
    prep_fcf<<<16, 64, 0, stream>>>(fcw, fcf);
    lstm_mfma<<<NBLK, 512, 0, stream>>>(wq2, s1p, biasp, wihh2, xh, fcf, fcb, out);
}